// Round 2
// baseline (294.006 us; speedup 1.0000x reference)
//
#include <hip/hip_runtime.h>

#define HH 512
#define WW 512
#define HW (HH*WW)
#define TS 32      // output tile
#define RT 48      // raw tile: TS + 2*8
#define AT 40      // centered tile: TS + 2*4
#define EPV 1e-20f

// Box window for center (y,x): rows y-3..y+4, cols x-3..x+4 (zero padded).
// All sums below use the d=1..8 offset convention relative to a tile whose
// origin is shifted by the halo (verified correct in R1).

// Stage an n x n tile (halo) of src into LDS. Interior blocks: float4 fast
// path, no bounds checks. Edge blocks: scalar checked path.
__device__ __forceinline__ void stage_tile(const float* __restrict__ src,
                                           float* __restrict__ dst,
                                           int n, int halo,
                                           int ty0, int tx0, int tid)
{
    const int y0 = ty0 - halo, x0 = tx0 - halo;
    const bool interior = (y0 >= 0) & (y0 + n <= HH) & (x0 >= 0) & (x0 + n <= WW);
    const int nf4 = n >> 2;
    if (interior) {
        for (int idx = tid; idx < n * nf4; idx += 256) {
            int r = idx / nf4, c = (idx - r * nf4) << 2;
            *(float4*)&dst[r * n + c] = *(const float4*)&src[(y0 + r) * WW + x0 + c];
        }
    } else {
        for (int idx = tid; idx < n * n; idx += 256) {
            int r = idx / n, c = idx - r * n;
            int gy = y0 + r, gx = x0 + c;
            float v = 0.f;
            if ((unsigned)gy < HH && (unsigned)gx < WW) v = src[gy * WW + gx];
            dst[r * n + c] = v;
        }
    }
}

__global__ __launch_bounds__(256) void prep_kernel(
    const float* __restrict__ outs, const float* __restrict__ labs,
    float* __restrict__ ac, float* __restrict__ bc,
    float* __restrict__ sii, float* __restrict__ sjj)
{
    __shared__ __align__(16) float raw[RT * RT];   // raw tile, halo 8
    __shared__ __align__(16) float hsb[RT * AT];   // horiz 8-sums of raw
    __shared__ __align__(16) float acs[AT * AT];   // centered, halo 4
    __shared__ __align__(16) float hs2[AT * TS];   // horiz 8-sums of acs^2

    const int z = blockIdx.z;
    const float* src; float* dst_c; float* dst_s;
    if (z < 24) { src = outs + z * HW;            dst_c = ac + z * HW;       dst_s = sii + z * HW; }
    else        { int t = z - 24; src = labs + t * HW; dst_c = bc + t * HW;  dst_s = sjj + t * HW; }

    const int ty0 = blockIdx.y * TS, tx0 = blockIdx.x * TS;
    const int tid = threadIdx.x;

    stage_tile(src, raw, RT, 8, ty0, tx0, tid);
    __syncthreads();

    // ---- horizontal 8-sums: hsb[r][q] = sum raw[r][q+1..q+8], running ----
    if (tid < 240) {
        int r = tid / 5, sg = tid % 5, x0 = sg * 8;
        float f[16];
        *(float4*)&f[0]  = *(const float4*)&raw[r * RT + x0];
        *(float4*)&f[4]  = *(const float4*)&raw[r * RT + x0 + 4];
        *(float4*)&f[8]  = *(const float4*)&raw[r * RT + x0 + 8];
        *(float4*)&f[12] = *(const float4*)&raw[r * RT + x0 + 12];
        float o[8];
        float s = f[1] + f[2] + f[3] + f[4] + f[5] + f[6] + f[7] + f[8];
        o[0] = s;
        #pragma unroll
        for (int q = 1; q < 8; ++q) { s += f[q + 8] - f[q]; o[q] = s; }
        *(float4*)&hsb[r * AT + x0]     = *(float4*)&o[0];
        *(float4*)&hsb[r * AT + x0 + 4] = *(float4*)&o[4];
    }
    __syncthreads();

    // ---- vertical 8-sums (running) -> mean -> acs = raw - mean (0 OOB) ----
    if (tid < 200) {
        int q = tid % 40, sp = tid / 40, p0 = sp * 8;
        float h[15];
        #pragma unroll
        for (int k = 0; k < 15; ++k) h[k] = hsb[(p0 + 1 + k) * AT + q];
        float v = h[0] + h[1] + h[2] + h[3] + h[4] + h[5] + h[6] + h[7];
        int gx = tx0 - 4 + q;
        bool okx = (unsigned)gx < WW;
        #pragma unroll
        for (int k = 0; k < 8; ++k) {
            if (k) v += h[k + 7] - h[k - 1];
            int p = p0 + k;
            int gy = ty0 - 4 + p;
            float val = 0.f;
            if (okx && (unsigned)gy < HH)
                val = raw[(p + 4) * RT + q + 4] - v * (1.0f / 64.0f);
            acs[p * AT + q] = val;
        }
    }
    __syncthreads();

    // ---- write centered center 32x32 (float4) ----
    {
        int y = tid >> 3, c = (tid & 7) << 2;
        *(float4*)&dst_c[(ty0 + y) * WW + tx0 + c] =
            *(const float4*)&acs[(y + 4) * AT + 4 + c];
    }

    // ---- horizontal 8-sums of acs^2 (running) ----
    if (tid < 160) {
        int r = tid >> 2, sg = tid & 3, x0 = sg * 8;
        float f[16];
        *(float4*)&f[0]  = *(const float4*)&acs[r * AT + x0];
        *(float4*)&f[4]  = *(const float4*)&acs[r * AT + x0 + 4];
        *(float4*)&f[8]  = *(const float4*)&acs[r * AT + x0 + 8];
        *(float4*)&f[12] = *(const float4*)&acs[r * AT + x0 + 12];
        #pragma unroll
        for (int k = 0; k < 16; ++k) f[k] *= f[k];
        float o[8];
        float s = f[1] + f[2] + f[3] + f[4] + f[5] + f[6] + f[7] + f[8];
        o[0] = s;
        #pragma unroll
        for (int q = 1; q < 8; ++q) { s += f[q + 8] - f[q]; o[q] = s; }
        *(float4*)&hs2[r * TS + x0]     = *(float4*)&o[0];
        *(float4*)&hs2[r * TS + x0 + 4] = *(float4*)&o[4];
    }
    __syncthreads();

    // ---- vertical 8-sums (running) -> sii ----
    if (tid < 128) {
        int x = tid & 31, sp = tid >> 5, y0 = sp * 8;
        float h[15];
        #pragma unroll
        for (int k = 0; k < 15; ++k) h[k] = hs2[(y0 + 1 + k) * TS + x];
        float v = h[0] + h[1] + h[2] + h[3] + h[4] + h[5] + h[6] + h[7];
        #pragma unroll
        for (int k = 0; k < 8; ++k) {
            if (k) v += h[k + 7] - h[k - 1];
            dst_s[(ty0 + y0 + k) * WW + tx0 + x] = fmaxf(v, EPV);
        }
    }
}

__global__ __launch_bounds__(256) void ncc_main_kernel(
    const float* __restrict__ ac, const float* __restrict__ bc,
    const float* __restrict__ sii, const float* __restrict__ sjj,
    float* __restrict__ out)
{
    __shared__ __align__(16) float at[AT * AT];
    __shared__ __align__(16) float bt[AT * AT];
    __shared__ __align__(16) float hs[AT * TS];
    __shared__ float wsum[4];

    const int z = blockIdx.z;          // b*6 + i
    const int b = z / 6;
    const int ty0 = blockIdx.y * TS, tx0 = blockIdx.x * TS;
    const int tid = threadIdx.x;

    const float* acp = ac + z * HW;
    const float* sip = sii + z * HW;

    stage_tile(acp, at, AT, 4, ty0, tx0, tid);

    // per-thread output pixels: col x, rows y0..y0+3
    const int x = tid & 31, y0 = (tid >> 5) << 2;
    float siir[4], m[4];
    #pragma unroll
    for (int r = 0; r < 4; ++r) {
        siir[r] = sip[(ty0 + y0 + r) * WW + tx0 + x];
        m[r] = -1.0f;
    }

    for (int j = 0; j < 4; ++j) {
        const float* bcp = bc + (b * 4 + j) * HW;
        const float* sjp = sjj + (b * 4 + j) * HW;

        stage_tile(bcp, bt, AT, 4, ty0, tx0, tid);
        __syncthreads();   // bt ready (also: prev vert's hs reads done)

        // horizontal 8-sums of product (running, vectorized)
        if (tid < 160) {
            int r = tid >> 2, sg = tid & 3, x0 = sg * 8;
            float fa[16], fb[16];
            *(float4*)&fa[0]  = *(const float4*)&at[r * AT + x0];
            *(float4*)&fa[4]  = *(const float4*)&at[r * AT + x0 + 4];
            *(float4*)&fa[8]  = *(const float4*)&at[r * AT + x0 + 8];
            *(float4*)&fa[12] = *(const float4*)&at[r * AT + x0 + 12];
            *(float4*)&fb[0]  = *(const float4*)&bt[r * AT + x0];
            *(float4*)&fb[4]  = *(const float4*)&bt[r * AT + x0 + 4];
            *(float4*)&fb[8]  = *(const float4*)&bt[r * AT + x0 + 8];
            *(float4*)&fb[12] = *(const float4*)&bt[r * AT + x0 + 12];
            float p[16];
            #pragma unroll
            for (int k = 0; k < 16; ++k) p[k] = fa[k] * fb[k];
            float o[8];
            float s = p[1] + p[2] + p[3] + p[4] + p[5] + p[6] + p[7] + p[8];
            o[0] = s;
            #pragma unroll
            for (int q = 1; q < 8; ++q) { s += p[q + 8] - p[q]; o[q] = s; }
            *(float4*)&hs[r * TS + x0]     = *(float4*)&o[0];
            *(float4*)&hs[r * TS + x0 + 4] = *(float4*)&o[4];
        }
        __syncthreads();

        // vertical 8-sums (running) -> sij -> cc -> running max
        {
            float h[11];
            #pragma unroll
            for (int k = 0; k < 11; ++k) h[k] = hs[(y0 + 1 + k) * TS + x];
            float v = h[0] + h[1] + h[2] + h[3] + h[4] + h[5] + h[6] + h[7];
            #pragma unroll
            for (int r = 0; r < 4; ++r) {
                if (r) v += h[r + 7] - h[r - 1];
                float sj = sjp[(ty0 + y0 + r) * WW + tx0 + x];
                float cc = v * __frsqrt_rn(fmaxf(siir[r] * sj, 1e-37f));
                m[r] = fmaxf(m[r], cc);
            }
        }
    }

    // X = 1 - clamp(m, -1, 1); m already >= -1
    float xs = 0.f;
    #pragma unroll
    for (int r = 0; r < 4; ++r) xs += 1.0f - fminf(m[r], 1.0f);

    #pragma unroll
    for (int off = 32; off > 0; off >>= 1) xs += __shfl_down(xs, off);
    if ((tid & 63) == 0) wsum[tid >> 6] = xs;
    __syncthreads();
    if (tid == 0) {
        float s = wsum[0] + wsum[1] + wsum[2] + wsum[3];
        atomicAdd(&out[1 + z], s * (1.0f / (float)HW));
        atomicAdd(&out[0],     s * (1.0f / (24.0f * (float)HW)));
    }
}

extern "C" void kernel_launch(void* const* d_in, const int* in_sizes, int n_in,
                              void* d_out, int out_size, void* d_ws, size_t ws_size,
                              hipStream_t stream) {
    const float* outs = (const float*)d_in[0];   // (4,6,512,512)
    const float* labs = (const float*)d_in[1];   // (4,4,512,512)
    float* out = (float*)d_out;                  // 25 floats
    float* ws = (float*)d_ws;

    float* acw = ws;                 // 24*HW
    float* bcw = acw + 24 * HW;      // 16*HW
    float* siw = bcw + 16 * HW;      // 24*HW
    float* sjw = siw + 24 * HW;      // 16*HW

    hipMemsetAsync(d_out, 0, out_size * sizeof(float), stream);

    prep_kernel<<<dim3(WW / TS, HH / TS, 40), 256, 0, stream>>>(outs, labs, acw, bcw, siw, sjw);
    ncc_main_kernel<<<dim3(WW / TS, HH / TS, 24), 256, 0, stream>>>(acw, bcw, siw, sjw, out);
}

// Round 3
// 277.742 us; speedup vs baseline: 1.0586x; 1.0586x over previous
//
#include <hip/hip_runtime.h>

#define HH 512
#define WW 512
#define HW (HH*WW)
#define TS 32      // output tile
#define RT 48      // raw tile: TS + 2*8
#define AT 40      // centered tile: TS + 2*4
#define RTS 52     // raw LDS stride  (52 mod 32 = 20 -> uniform banks for b128)
#define ATS 44     // AT  LDS stride  (44 mod 32 = 12 -> uniform banks for b128)
#define HSS 36     // hs  LDS stride  (36 mod 32 = 4  -> uniform banks)
#define EPV 1e-20f

// Box window for center (y,x): rows y-3..y+4, cols x-3..x+4 (zero padded).
// All sums use the d=1..8 offset convention relative to a halo-shifted tile
// (verified correct in R1/R2, absmax 0.0).

template<int N, int STRIDE, int HALO>
__device__ __forceinline__ void stage_tile(const float* __restrict__ src,
                                           float* __restrict__ dst,
                                           int ty0, int tx0, int tid)
{
    const int y0 = ty0 - HALO, x0 = tx0 - HALO;
    constexpr int NF4 = N / 4;
    if (y0 >= 0 && y0 + N <= HH && x0 >= 0 && x0 + N <= WW) {
        for (int idx = tid; idx < N * NF4; idx += 256) {
            int r = idx / NF4, c = (idx % NF4) << 2;
            *(float4*)&dst[r * STRIDE + c] = *(const float4*)&src[(y0 + r) * WW + x0 + c];
        }
    } else {
        for (int idx = tid; idx < N * N; idx += 256) {
            int r = idx / N, c = idx % N;
            int gy = y0 + r, gx = x0 + c;
            float v = 0.f;
            if ((unsigned)gy < HH && (unsigned)gx < WW) v = src[gy * WW + gx];
            dst[r * STRIDE + c] = v;
        }
    }
}

__global__ __launch_bounds__(256) void prep_kernel(
    const float* __restrict__ outs, const float* __restrict__ labs,
    float* __restrict__ ac, float* __restrict__ bc,
    float* __restrict__ sii, float* __restrict__ sjj)
{
    // raw (48x52=2496) and hs2 (40x36=1440) are aliased: raw's last read is in
    // vert-1, hs2 is first written after the following barrier.
    __shared__ __align__(16) float rawhs2[RT * RTS];
    __shared__ __align__(16) float hsb[RT * ATS];     // horiz 8-sums of raw
    __shared__ __align__(16) float acs[AT * ATS];     // centered, halo 4
    float* raw = rawhs2;
    float* hs2 = rawhs2;

    const int z = blockIdx.z;
    const float* src; float* dst_c; float* dst_s;
    if (z < 24) { src = outs + z * HW;            dst_c = ac + z * HW;       dst_s = sii + z * HW; }
    else        { int t = z - 24; src = labs + t * HW; dst_c = bc + t * HW;  dst_s = sjj + t * HW; }

    const int ty0 = blockIdx.y * TS, tx0 = blockIdx.x * TS;
    const int tid = threadIdx.x;

    stage_tile<RT, RTS, 8>(src, raw, ty0, tx0, tid);
    __syncthreads();

    // ---- horizontal 8-sums of raw (running): 48 rows x 5 segs ----
    if (tid < 240) {
        int r = tid / 5, sg = tid % 5, xc = sg * 8;
        float f[16];
        *(float4*)&f[0]  = *(const float4*)&raw[r * RTS + xc];
        *(float4*)&f[4]  = *(const float4*)&raw[r * RTS + xc + 4];
        *(float4*)&f[8]  = *(const float4*)&raw[r * RTS + xc + 8];
        *(float4*)&f[12] = *(const float4*)&raw[r * RTS + xc + 12];
        float o[8];
        float s = f[1] + f[2] + f[3] + f[4] + f[5] + f[6] + f[7] + f[8];
        o[0] = s;
        #pragma unroll
        for (int q = 1; q < 8; ++q) { s += f[q + 8] - f[q]; o[q] = s; }
        *(float4*)&hsb[r * ATS + xc]     = *(float4*)&o[0];
        *(float4*)&hsb[r * ATS + xc + 4] = *(float4*)&o[4];
    }
    __syncthreads();

    // ---- vertical 8-sums (running) -> mean -> acs = raw - mean (0 OOB) ----
    if (tid < 200) {
        int q = tid % 40, sp = tid / 40, p0 = sp * 8;
        float h[15];
        #pragma unroll
        for (int k = 0; k < 15; ++k) h[k] = hsb[(p0 + 1 + k) * ATS + q];
        float v = h[0] + h[1] + h[2] + h[3] + h[4] + h[5] + h[6] + h[7];
        int gx = tx0 - 4 + q;
        bool okx = (unsigned)gx < WW;
        #pragma unroll
        for (int k = 0; k < 8; ++k) {
            if (k) v += h[k + 7] - h[k - 1];
            int p = p0 + k;
            int gy = ty0 - 4 + p;
            float val = 0.f;
            if (okx && (unsigned)gy < HH)
                val = raw[(p + 4) * RTS + q + 4] - v * (1.0f / 64.0f);
            acs[p * ATS + q] = val;
        }
    }
    __syncthreads();   // raw dead from here; hs2 may overwrite it

    // ---- write centered center 32x32 (float4) ----
    {
        int y = tid >> 3, c = (tid & 7) << 2;
        *(float4*)&dst_c[(ty0 + y) * WW + tx0 + c] =
            *(const float4*)&acs[(y + 4) * ATS + 4 + c];
    }

    // ---- horizontal 8-sums of acs^2 (running): 40 rows x 4 segs ----
    if (tid < 160) {
        int r = tid >> 2, sg = tid & 3, xc = sg * 8;
        float f[16];
        *(float4*)&f[0]  = *(const float4*)&acs[r * ATS + xc];
        *(float4*)&f[4]  = *(const float4*)&acs[r * ATS + xc + 4];
        *(float4*)&f[8]  = *(const float4*)&acs[r * ATS + xc + 8];
        *(float4*)&f[12] = *(const float4*)&acs[r * ATS + xc + 12];
        #pragma unroll
        for (int k = 0; k < 16; ++k) f[k] *= f[k];
        float o[8];
        float s = f[1] + f[2] + f[3] + f[4] + f[5] + f[6] + f[7] + f[8];
        o[0] = s;
        #pragma unroll
        for (int q = 1; q < 8; ++q) { s += f[q + 8] - f[q]; o[q] = s; }
        *(float4*)&hs2[r * HSS + xc]     = *(float4*)&o[0];
        *(float4*)&hs2[r * HSS + xc + 4] = *(float4*)&o[4];
    }
    __syncthreads();

    // ---- vertical 8-sums (running) -> sii ----
    if (tid < 128) {
        int x = tid & 31, sp = tid >> 5, y0 = sp * 8;
        float h[15];
        #pragma unroll
        for (int k = 0; k < 15; ++k) h[k] = hs2[(y0 + 1 + k) * HSS + x];
        float v = h[0] + h[1] + h[2] + h[3] + h[4] + h[5] + h[6] + h[7];
        #pragma unroll
        for (int k = 0; k < 8; ++k) {
            if (k) v += h[k + 7] - h[k - 1];
            dst_s[(ty0 + y0 + k) * WW + tx0 + x] = fmaxf(v, EPV);
        }
    }
}

__global__ __launch_bounds__(256) void ncc_main_kernel(
    const float* __restrict__ ac, const float* __restrict__ bc,
    const float* __restrict__ sii, const float* __restrict__ sjj,
    float* __restrict__ out)
{
    __shared__ __align__(16) float at[AT * ATS];       // 1760
    __shared__ __align__(16) float bt[2][AT * ATS];    // double-buffered bc tile
    __shared__ __align__(16) float hs[AT * HSS];       // 1440
    __shared__ float wsum[4];

    const int z = blockIdx.z;          // b*6 + i
    const int b = z / 6;
    const int ty0 = blockIdx.y * TS, tx0 = blockIdx.x * TS;
    const int tid = threadIdx.x;

    const float* acp = ac + z * HW;
    const float* sip = sii + z * HW;

    const bool inter = (ty0 - 4 >= 0) && (ty0 - 4 + AT <= HH) &&
                       (tx0 - 4 >= 0) && (tx0 - 4 + AT <= WW);

    stage_tile<AT, ATS, 4>(acp, at, ty0, tx0, tid);
    stage_tile<AT, ATS, 4>(bc + b * 4 * HW, bt[0], ty0, tx0, tid);

    // per-thread output pixels: col x, rows y0..y0+3
    const int x = tid & 31, y0 = (tid >> 5) << 2;
    float siir[4], m[4];
    #pragma unroll
    for (int r = 0; r < 4; ++r) {
        siir[r] = sip[(ty0 + y0 + r) * WW + tx0 + x];
        m[r] = -1.0f;
    }

    // prefetch mapping for interior bc tiles: 400 float4 units
    const int pr0 = tid / 10,         pc0 = (tid % 10) << 2;
    const int i1  = tid + 256;
    const int pr1 = i1 / 10,          pc1 = (i1 % 10) << 2;

    __syncthreads();

    for (int j = 0; j < 4; ++j) {
        const int cur = j & 1;
        const float* sjp = sjj + (b * 4 + j) * HW;

        // prefetch per-thread sjj values (loads issue early, consumed in vert)
        float sjr[4];
        #pragma unroll
        for (int r = 0; r < 4; ++r)
            sjr[r] = sjp[(ty0 + y0 + r) * WW + tx0 + x];

        // prefetch next bc tile
        float4 p0v, p1v;
        if (j < 3) {
            const float* bcn = bc + (b * 4 + j + 1) * HW;
            if (inter) {
                p0v = *(const float4*)&bcn[(ty0 - 4 + pr0) * WW + tx0 - 4 + pc0];
                if (i1 < 400)
                    p1v = *(const float4*)&bcn[(ty0 - 4 + pr1) * WW + tx0 - 4 + pc1];
            } else {
                stage_tile<AT, ATS, 4>(bcn, bt[1 ^ cur], ty0, tx0, tid);
            }
        }

        // horizontal 8-sums of product (running): 40 rows x 4 segs
        if (tid < 160) {
            int r = tid >> 2, sg = tid & 3, xc = sg * 8;
            const float* arow = &at[r * ATS + xc];
            const float* brow = &bt[cur][r * ATS + xc];
            float fa[16], fb[16];
            *(float4*)&fa[0]  = *(const float4*)&arow[0];
            *(float4*)&fa[4]  = *(const float4*)&arow[4];
            *(float4*)&fa[8]  = *(const float4*)&arow[8];
            *(float4*)&fa[12] = *(const float4*)&arow[12];
            *(float4*)&fb[0]  = *(const float4*)&brow[0];
            *(float4*)&fb[4]  = *(const float4*)&brow[4];
            *(float4*)&fb[8]  = *(const float4*)&brow[8];
            *(float4*)&fb[12] = *(const float4*)&brow[12];
            float p[16];
            #pragma unroll
            for (int k = 0; k < 16; ++k) p[k] = fa[k] * fb[k];
            float o[8];
            float s = p[1] + p[2] + p[3] + p[4] + p[5] + p[6] + p[7] + p[8];
            o[0] = s;
            #pragma unroll
            for (int q = 1; q < 8; ++q) { s += p[q + 8] - p[q]; o[q] = s; }
            *(float4*)&hs[r * HSS + xc]     = *(float4*)&o[0];
            *(float4*)&hs[r * HSS + xc + 4] = *(float4*)&o[4];
        }

        // commit prefetched bc tile to the other buffer
        if (j < 3 && inter) {
            *(float4*)&bt[1 ^ cur][pr0 * ATS + pc0] = p0v;
            if (i1 < 400) *(float4*)&bt[1 ^ cur][pr1 * ATS + pc1] = p1v;
        }
        __syncthreads();   // hs ready; bt[next] ready

        // vertical 8-sums (running) -> sij -> cc -> running max
        {
            float h[11];
            #pragma unroll
            for (int k = 0; k < 11; ++k) h[k] = hs[(y0 + 1 + k) * HSS + x];
            float v = h[0] + h[1] + h[2] + h[3] + h[4] + h[5] + h[6] + h[7];
            #pragma unroll
            for (int r = 0; r < 4; ++r) {
                if (r) v += h[r + 7] - h[r - 1];
                float cc = v * __frsqrt_rn(fmaxf(siir[r] * sjr[r], 1e-37f));
                m[r] = fmaxf(m[r], cc);
            }
        }
        __syncthreads();   // hs reads done before next j's horiz rewrites
    }

    // X = 1 - clamp(m, -1, 1); m already >= -1
    float xs = 0.f;
    #pragma unroll
    for (int r = 0; r < 4; ++r) xs += 1.0f - fminf(m[r], 1.0f);

    #pragma unroll
    for (int off = 32; off > 0; off >>= 1) xs += __shfl_down(xs, off);
    if ((tid & 63) == 0) wsum[tid >> 6] = xs;
    __syncthreads();
    if (tid == 0) {
        float s = wsum[0] + wsum[1] + wsum[2] + wsum[3];
        atomicAdd(&out[1 + z], s * (1.0f / (float)HW));
        atomicAdd(&out[0],     s * (1.0f / (24.0f * (float)HW)));
    }
}

extern "C" void kernel_launch(void* const* d_in, const int* in_sizes, int n_in,
                              void* d_out, int out_size, void* d_ws, size_t ws_size,
                              hipStream_t stream) {
    const float* outs = (const float*)d_in[0];   // (4,6,512,512)
    const float* labs = (const float*)d_in[1];   // (4,4,512,512)
    float* out = (float*)d_out;                  // 25 floats
    float* ws = (float*)d_ws;

    float* acw = ws;                 // 24*HW
    float* bcw = acw + 24 * HW;      // 16*HW
    float* siw = bcw + 16 * HW;      // 24*HW
    float* sjw = siw + 24 * HW;      // 16*HW

    hipMemsetAsync(d_out, 0, out_size * sizeof(float), stream);

    prep_kernel<<<dim3(WW / TS, HH / TS, 40), 256, 0, stream>>>(outs, labs, acw, bcw, siw, sjw);
    ncc_main_kernel<<<dim3(WW / TS, HH / TS, 24), 256, 0, stream>>>(acw, bcw, siw, sjw, out);
}

// Round 4
// 236.811 us; speedup vs baseline: 1.2415x; 1.1728x over previous
//
#include <hip/hip_runtime.h>

#define HH 512
#define WW 512
#define HW (HH*WW)
#define TS 32      // output tile
#define RT 48      // raw tile: TS + 2*8
#define AT 40      // centered tile: TS + 2*4
#define RTS 52     // raw LDS stride  (mod 32 = 20 -> uniform banks for b128)
#define ATS 44     // AT  LDS stride  (mod 32 = 12 -> uniform banks)
#define HSS 36     // hs  LDS stride  (mod 32 = 4  -> uniform banks)
#define EPV 1e-20f

// Box window for center (y,x): rows y-3..y+4, cols x-3..x+4 (zero padded).
// All sums use the d=1..8 offset convention relative to a halo-shifted tile
// (verified absmax 0.0 in R1-R3).

template<int N, int STRIDE, int HALO>
__device__ __forceinline__ void stage_tile(const float* __restrict__ src,
                                           float* __restrict__ dst,
                                           int ty0, int tx0, int tid)
{
    const int y0 = ty0 - HALO, x0 = tx0 - HALO;
    constexpr int NF4 = N / 4;
    if (y0 >= 0 && y0 + N <= HH && x0 >= 0 && x0 + N <= WW) {
        for (int idx = tid; idx < N * NF4; idx += 256) {
            int r = idx / NF4, c = (idx % NF4) << 2;
            *(float4*)&dst[r * STRIDE + c] = *(const float4*)&src[(y0 + r) * WW + x0 + c];
        }
    } else {
        for (int idx = tid; idx < N * N; idx += 256) {
            int r = idx / N, c = idx % N;
            int gy = y0 + r, gx = x0 + c;
            float v = 0.f;
            if ((unsigned)gy < HH && (unsigned)gx < WW) v = src[gy * WW + gx];
            dst[r * STRIDE + c] = v;
        }
    }
}

// horizontal running 8-sums of raw (48 rows x 40 cols), tid<240
__device__ __forceinline__ void horiz_raw(const float* __restrict__ raw,
                                          float* __restrict__ hsb, int tid)
{
    if (tid < 240) {
        int r = tid / 5, sg = tid % 5, xc = sg * 8;
        float f[16];
        *(float4*)&f[0]  = *(const float4*)&raw[r * RTS + xc];
        *(float4*)&f[4]  = *(const float4*)&raw[r * RTS + xc + 4];
        *(float4*)&f[8]  = *(const float4*)&raw[r * RTS + xc + 8];
        *(float4*)&f[12] = *(const float4*)&raw[r * RTS + xc + 12];
        float o[8];
        float s = f[1] + f[2] + f[3] + f[4] + f[5] + f[6] + f[7] + f[8];
        o[0] = s;
        #pragma unroll
        for (int q = 1; q < 8; ++q) { s += f[q + 8] - f[q]; o[q] = s; }
        *(float4*)&hsb[r * ATS + xc]     = *(float4*)&o[0];
        *(float4*)&hsb[r * ATS + xc + 4] = *(float4*)&o[4];
    }
}

// vertical running 8-sums of hsb -> mean; dst = raw - mean (0 OOB), tid<200
__device__ __forceinline__ void vert_center(const float* __restrict__ hsb,
                                            const float* __restrict__ raw,
                                            float* __restrict__ dst,
                                            int ty0, int tx0, int tid)
{
    if (tid < 200) {
        int q = tid % 40, sp = tid / 40, p0 = sp * 8;
        float h[15];
        #pragma unroll
        for (int k = 0; k < 15; ++k) h[k] = hsb[(p0 + 1 + k) * ATS + q];
        float v = h[0] + h[1] + h[2] + h[3] + h[4] + h[5] + h[6] + h[7];
        int gx = tx0 - 4 + q;
        bool okx = (unsigned)gx < WW;
        #pragma unroll
        for (int k = 0; k < 8; ++k) {
            if (k) v += h[k + 7] - h[k - 1];
            int p = p0 + k;
            int gy = ty0 - 4 + p;
            float val = 0.f;
            if (okx && (unsigned)gy < HH)
                val = raw[(p + 4) * RTS + q + 4] - v * (1.0f / 64.0f);
            dst[p * ATS + q] = val;
        }
    }
}

__global__ __launch_bounds__(256) void ncc_fused_kernel(
    const float* __restrict__ outs, const float* __restrict__ labs,
    float* __restrict__ out)
{
    __shared__ __align__(16) float raw[RT * RTS];   // 2496 f
    __shared__ __align__(16) float hsbu[2 * AT * HSS]; // union: hsb(2112) | hs+hs2(2880)
    __shared__ __align__(16) float acs[AT * ATS];   // 1760 f
    __shared__ __align__(16) float bcs[AT * ATS];   // 1760 f
    __shared__ float wsum[4];

    float* hsb = hsbu;
    float* hs  = hsbu;                 // b^2 sums (and a^2 in prep)
    float* hs2 = hsbu + AT * HSS;      // product sums

    const int z = blockIdx.z;          // b*6 + i
    const int b = z / 6;
    const int ty0 = blockIdx.y * TS, tx0 = blockIdx.x * TS;
    const int tid = threadIdx.x;

    // ---- a-prep: raw a -> acs, sii (regs) ----
    stage_tile<RT, RTS, 8>(outs + z * HW, raw, ty0, tx0, tid);
    __syncthreads();
    horiz_raw(raw, hsb, tid);
    __syncthreads();
    vert_center(hsb, raw, acs, ty0, tx0, tid);
    __syncthreads();

    // horiz 8-sums of acs^2 -> hs (overwrites hsb region; hsb dead)
    if (tid < 160) {
        int r = tid >> 2, sg = tid & 3, xc = sg * 8;
        float f[16];
        *(float4*)&f[0]  = *(const float4*)&acs[r * ATS + xc];
        *(float4*)&f[4]  = *(const float4*)&acs[r * ATS + xc + 4];
        *(float4*)&f[8]  = *(const float4*)&acs[r * ATS + xc + 8];
        *(float4*)&f[12] = *(const float4*)&acs[r * ATS + xc + 12];
        #pragma unroll
        for (int k = 0; k < 16; ++k) f[k] *= f[k];
        float o[8];
        float s = f[1] + f[2] + f[3] + f[4] + f[5] + f[6] + f[7] + f[8];
        o[0] = s;
        #pragma unroll
        for (int q = 1; q < 8; ++q) { s += f[q + 8] - f[q]; o[q] = s; }
        *(float4*)&hs[r * HSS + xc]     = *(float4*)&o[0];
        *(float4*)&hs[r * HSS + xc + 4] = *(float4*)&o[4];
    }
    __syncthreads();

    // vert 8-sums -> sii in regs (per-thread 4 pixels: col x, rows y0..y0+3)
    const int x = tid & 31, y0 = (tid >> 5) << 2;
    float sii_r[4], m[4];
    {
        float h[11];
        #pragma unroll
        for (int k = 0; k < 11; ++k) h[k] = hs[(y0 + 1 + k) * HSS + x];
        float v = h[0] + h[1] + h[2] + h[3] + h[4] + h[5] + h[6] + h[7];
        #pragma unroll
        for (int r = 0; r < 4; ++r) {
            if (r) v += h[r + 7] - h[r - 1];
            sii_r[r] = fmaxf(v, EPV);
            m[r] = -1.0f;
        }
    }

    // ---- per-j: raw b -> bcs, sjj; product -> cc -> max ----
    for (int j = 0; j < 4; ++j) {
        __syncthreads();   // hs/hs2 reads done before raw/hsb rewrites
        stage_tile<RT, RTS, 8>(labs + (b * 4 + j) * HW, raw, ty0, tx0, tid);
        __syncthreads();
        horiz_raw(raw, hsb, tid);
        __syncthreads();
        vert_center(hsb, raw, bcs, ty0, tx0, tid);
        __syncthreads();

        // fused horiz: product (acs*bcs) -> hs2, square (bcs^2) -> hs
        if (tid < 160) {
            int r = tid >> 2, sg = tid & 3, xc = sg * 8;
            float fa[16], fb[16];
            *(float4*)&fa[0]  = *(const float4*)&acs[r * ATS + xc];
            *(float4*)&fa[4]  = *(const float4*)&acs[r * ATS + xc + 4];
            *(float4*)&fa[8]  = *(const float4*)&acs[r * ATS + xc + 8];
            *(float4*)&fa[12] = *(const float4*)&acs[r * ATS + xc + 12];
            *(float4*)&fb[0]  = *(const float4*)&bcs[r * ATS + xc];
            *(float4*)&fb[4]  = *(const float4*)&bcs[r * ATS + xc + 4];
            *(float4*)&fb[8]  = *(const float4*)&bcs[r * ATS + xc + 8];
            *(float4*)&fb[12] = *(const float4*)&bcs[r * ATS + xc + 12];
            float p[16], q2[16];
            #pragma unroll
            for (int k = 0; k < 16; ++k) { p[k] = fa[k] * fb[k]; q2[k] = fb[k] * fb[k]; }
            float op[8], oq[8];
            float sp = p[1]+p[2]+p[3]+p[4]+p[5]+p[6]+p[7]+p[8];
            float sq = q2[1]+q2[2]+q2[3]+q2[4]+q2[5]+q2[6]+q2[7]+q2[8];
            op[0] = sp; oq[0] = sq;
            #pragma unroll
            for (int q = 1; q < 8; ++q) {
                sp += p[q + 8] - p[q];  op[q] = sp;
                sq += q2[q + 8] - q2[q]; oq[q] = sq;
            }
            *(float4*)&hs2[r * HSS + xc]     = *(float4*)&op[0];
            *(float4*)&hs2[r * HSS + xc + 4] = *(float4*)&op[4];
            *(float4*)&hs[r * HSS + xc]      = *(float4*)&oq[0];
            *(float4*)&hs[r * HSS + xc + 4]  = *(float4*)&oq[4];
        }
        __syncthreads();

        // fused vert: sij and sjj -> cc -> running max
        {
            float hp[11], hq[11];
            #pragma unroll
            for (int k = 0; k < 11; ++k) {
                hp[k] = hs2[(y0 + 1 + k) * HSS + x];
                hq[k] = hs[(y0 + 1 + k) * HSS + x];
            }
            float vp = hp[0]+hp[1]+hp[2]+hp[3]+hp[4]+hp[5]+hp[6]+hp[7];
            float vq = hq[0]+hq[1]+hq[2]+hq[3]+hq[4]+hq[5]+hq[6]+hq[7];
            #pragma unroll
            for (int r = 0; r < 4; ++r) {
                if (r) { vp += hp[r + 7] - hp[r - 1]; vq += hq[r + 7] - hq[r - 1]; }
                float sjj = fmaxf(vq, EPV);
                float cc = vp * __frsqrt_rn(fmaxf(sii_r[r] * sjj, 1e-37f));
                m[r] = fmaxf(m[r], cc);
            }
        }
    }

    // X = 1 - clamp(m, -1, 1); m already >= -1
    float xs = 0.f;
    #pragma unroll
    for (int r = 0; r < 4; ++r) xs += 1.0f - fminf(m[r], 1.0f);

    #pragma unroll
    for (int off = 32; off > 0; off >>= 1) xs += __shfl_down(xs, off);
    if ((tid & 63) == 0) wsum[tid >> 6] = xs;
    __syncthreads();
    if (tid == 0) {
        float s = wsum[0] + wsum[1] + wsum[2] + wsum[3];
        atomicAdd(&out[1 + z], s * (1.0f / (float)HW));
    }
}

__global__ void finalize_kernel(float* __restrict__ out)
{
    if (threadIdx.x == 0) {
        float s = 0.f;
        #pragma unroll
        for (int z = 0; z < 24; ++z) s += out[1 + z];
        out[0] = s * (1.0f / 24.0f);
    }
}

extern "C" void kernel_launch(void* const* d_in, const int* in_sizes, int n_in,
                              void* d_out, int out_size, void* d_ws, size_t ws_size,
                              hipStream_t stream) {
    const float* outs = (const float*)d_in[0];   // (4,6,512,512)
    const float* labs = (const float*)d_in[1];   // (4,4,512,512)
    float* out = (float*)d_out;                  // 25 floats

    hipMemsetAsync(d_out, 0, out_size * sizeof(float), stream);

    ncc_fused_kernel<<<dim3(WW / TS, HH / TS, 24), 256, 0, stream>>>(outs, labs, out);
    finalize_kernel<<<1, 64, 0, stream>>>(out);
}

// Round 5
// 196.012 us; speedup vs baseline: 1.4999x; 1.2081x over previous
//
#include <hip/hip_runtime.h>

#define HH 512
#define WW 512
#define HW (HH*WW)
#define EPV 1e-20f

// Box window for center (y,x): rows y-3..y+4, cols x-3..x+4, zero-padded
// (verified absmax 0.0 in R1-R4). Streaming formulation:
//   h(row r, lane l) = sum_{d=1..8} v(r, l+d)   [horizontal, via bpermute]
//   S(y) = sum_{c=y-3..y+4} h(c)                [vertical, register ring]

__device__ __forceinline__ float bpf(int addr, float v) {
    return __int_as_float(__builtin_amdgcn_ds_bpermute(addr, __float_as_int(v)));
}

// h(l) = sum_{d=1..8} v(l+d); valid for lanes l <= 55 (wave64).
// log-doubling: t1=v(l)+v(l+1); t2=t1(l)+t1(l+2); t4=t2(l)+t2(l+4)=sum v(l..l+7);
// h(l)=t4(l+1).
__device__ __forceinline__ float win8(float v, int a1, int a2, int a4) {
    float t = v + bpf(a1, v);
    t = t + bpf(a2, t);
    t = t + bpf(a4, t);
    return bpf(a1, t);
}

// ---------------- prep: raw -> centered (ac/bc) + variance box (sii/sjj) ----
// One wave per (image z, 48-col strip s, 64-row seg). Two-stage cascade:
//   stage1: ha = win8(raw row r) -> ring(8) -> VA = box sum -> mu(c=r-4)
//           acv(c) = (raw(c) - VA/64) * colmask   [0 outside image]
//   stage2: hii = win8(acv^2) -> ring(8) -> VSII -> sii(y=c-4)
// Stream t=0..79 (10 x unroll-8 so all ring indices are static).
__global__ __launch_bounds__(64) void prep_stream(
    const float* __restrict__ outs, const float* __restrict__ labs,
    float* __restrict__ ac, float* __restrict__ bc,
    float* __restrict__ sii, float* __restrict__ sjj)
{
    const int l  = threadIdx.x;
    const int x0 = 48 * blockIdx.x;          // strip start (output cols)
    const int y0 = 64 * blockIdx.y;          // seg start (output rows)
    const int z  = blockIdx.z;

    const float* src; float* cdst; float* sdst;
    if (z < 24) { src = outs + z * HW; cdst = ac + z * HW; sdst = sii + z * HW; }
    else { int u = z - 24; src = labs + u * HW; cdst = bc + u * HW; sdst = sjj + u * HW; }

    const int   gin  = x0 - 4 + l;                       // input col for this lane
    const int   ginc = min(max(gin, 0), WW - 1);
    const float minA = (gin >= 0 && gin < WW) ? 1.f : 0.f;
    const int   a1 = ((l + 1) & 63) << 2, a2 = ((l + 2) & 63) << 2, a4 = ((l + 4) & 63) << 2;

    const bool st_c = (l >= 4 && l < 52 && gin < WW);    // ac store: col gin, lanes 4..51
    const int  gout = x0 + l;                            // sii store col, lanes 0..47
    const bool st_s = (l < 48 && gout < WW);

    float araw[8], ha8[8], hii8[8];
    #pragma unroll
    for (int k = 0; k < 8; ++k) { araw[k] = 0.f; ha8[k] = 0.f; hii8[k] = 0.f; }
    float VA = 0.f, VSII = 0.f;

    for (int g = 0; g < 10; ++g) {
        #pragma unroll
        for (int k = 0; k < 8; ++k) {
            const int t = g * 8 + k;
            const int r = y0 - 7 + t;                    // stage-1 input row
            float av = 0.f;
            if (r >= 0 && r < HH) av = src[r * WW + ginc] * minA;
            float han = win8(av, a1, a2, a4);
            VA += han - ha8[k]; ha8[k] = han;            // VA = box rows r-7..r = c-3..c+4
            float aold = araw[(k + 4) & 7];              // raw row c = r-4
            araw[k] = av;
            if (t >= 8 && t <= 78) {
                const int c = r - 4;
                float acv = 0.f;
                if (c >= 0 && c < HH) acv = (aold - VA * (1.f / 64.f)) * minA;
                if (c >= y0 && c < y0 + 64 && c < HH && st_c)
                    cdst[c * WW + gin] = acv;
                float hin = win8(acv * acv, a1, a2, a4);
                VSII += hin - hii8[k]; hii8[k] = hin;    // VSII = box rows c-7..c = y-3..y+4
                if (t >= 15) {
                    const int y = c - 4;                 // y in [y0, y0+63]
                    if (st_s) sdst[y * WW + gout] = fmaxf(VSII, EPV);
                }
            }
        }
    }
}

// ---------------- main: sij streaming, all 4 j per wave --------------------
// One wave per (z=b*6+i, 56-col strip, 32-row seg). Reads precomputed
// ac/bc/sii/sjj. Per step c: p_j = ac*bc_j, h_j = win8(p_j), ring -> VS_j;
// emit y=c-4: cc_j = VS_j * rsqrt(sii*sjj), max over j, accumulate X.
// Stream t=0..39 (5 x unroll-8). Zero barriers, zero LDS arrays.
__global__ __launch_bounds__(64) void ncc_stream(
    const float* __restrict__ ac, const float* __restrict__ bc,
    const float* __restrict__ sii, const float* __restrict__ sjj,
    float* __restrict__ out)
{
    const int l  = threadIdx.x;
    const int x0 = 56 * blockIdx.x;
    const int y0 = 32 * blockIdx.y;
    const int z  = blockIdx.z;               // b*6 + i
    const int b  = z / 6;

    const float* acp = ac  + z * HW;
    const float* sip = sii + z * HW;
    const float* bcp[4]; const float* sjp[4];
    #pragma unroll
    for (int j = 0; j < 4; ++j) {
        bcp[j] = bc  + (b * 4 + j) * HW;
        sjp[j] = sjj + (b * 4 + j) * HW;
    }

    const int   gin  = x0 - 4 + l;
    const int   ginc = min(max(gin, 0), WW - 1);
    const float minA = (gin >= 0 && gin < WW) ? 1.f : 0.f;
    const int   gout = x0 + l;
    const int   goutc = min(gout, WW - 1);
    const float outm = (l < 56 && gout < WW) ? 1.f : 0.f;
    const int   a1 = ((l + 1) & 63) << 2, a2 = ((l + 2) & 63) << 2, a4 = ((l + 4) & 63) << 2;

    float ring[4][8], VS[4];
    #pragma unroll
    for (int j = 0; j < 4; ++j) {
        VS[j] = 0.f;
        #pragma unroll
        for (int k = 0; k < 8; ++k) ring[j][k] = 0.f;
    }
    float xs = 0.f;

    for (int g = 0; g < 5; ++g) {
        #pragma unroll
        for (int k = 0; k < 8; ++k) {
            const int t = g * 8 + k;
            const int c = y0 - 3 + t;                    // product row
            float av = 0.f, bv[4] = {0.f, 0.f, 0.f, 0.f};
            if (c >= 0 && c < HH) {
                const int ro = c * WW + ginc;
                av = acp[ro] * minA;
                #pragma unroll
                for (int j = 0; j < 4; ++j) bv[j] = bcp[j][ro] * minA;
            }
            #pragma unroll
            for (int j = 0; j < 4; ++j) {
                float h = win8(av * bv[j], a1, a2, a4);
                VS[j] += h - ring[j][k]; ring[j][k] = h;  // VS = box rows c-7..c
            }
            if (t >= 7 && t <= 38) {
                const int y  = y0 + t - 7;               // = c-4, in [y0, y0+31]
                const int yo = y * WW + goutc;
                float si = sip[yo];
                float mm = -1.f;
                #pragma unroll
                for (int j = 0; j < 4; ++j) {
                    float sj = sjp[j][yo];
                    float cc = VS[j] * __frsqrt_rn(fmaxf(si * sj, 1e-37f));
                    mm = fmaxf(mm, cc);
                }
                xs += outm * (1.f - fminf(mm, 1.f));
            }
        }
    }

    #pragma unroll
    for (int off = 32; off > 0; off >>= 1) xs += __shfl_down(xs, off);
    if (l == 0) atomicAdd(&out[1 + z], xs * (1.f / (float)HW));
}

__global__ void finalize_kernel(float* __restrict__ out)
{
    if (threadIdx.x == 0) {
        float s = 0.f;
        #pragma unroll
        for (int z = 0; z < 24; ++z) s += out[1 + z];
        out[0] = s * (1.0f / 24.0f);
    }
}

extern "C" void kernel_launch(void* const* d_in, const int* in_sizes, int n_in,
                              void* d_out, int out_size, void* d_ws, size_t ws_size,
                              hipStream_t stream) {
    const float* outs = (const float*)d_in[0];   // (4,6,512,512)
    const float* labs = (const float*)d_in[1];   // (4,4,512,512)
    float* out = (float*)d_out;                  // 25 floats
    float* ws  = (float*)d_ws;

    float* acw = ws;                 // 24*HW
    float* bcw = acw + 24 * HW;      // 16*HW
    float* siw = bcw + 16 * HW;      // 24*HW
    float* sjw = siw + 24 * HW;      // 16*HW

    hipMemsetAsync(d_out, 0, out_size * sizeof(float), stream);

    // prep: 11 strips of 48 cols x 8 segs of 64 rows x 40 images, 1 wave each
    prep_stream<<<dim3(11, 8, 40), 64, 0, stream>>>(outs, labs, acw, bcw, siw, sjw);
    // main: 10 strips of 56 cols x 16 segs of 32 rows x 24 (b,i), 1 wave each
    ncc_stream<<<dim3(10, 16, 24), 64, 0, stream>>>(acw, bcw, siw, sjw, out);
    finalize_kernel<<<1, 64, 0, stream>>>(out);
}